// Round 15
// baseline (79.778 us; speedup 1.0000x reference)
//
#include <hip/hip_runtime.h>
#include <hip/hip_bf16.h>
#include <cstddef>
#include <cstdint>

#define BB 4
#define CC 256
#define II 32
#define NN 4096

// 1/sqrt(32) * log2(e): fold softmax scale AND exp->exp2 conversion into q.
#define SCALE_Q 0.25505572751402893f

typedef __attribute__((ext_vector_type(8))) short bf16x8;
typedef __attribute__((ext_vector_type(16))) float f32x16;

static __device__ __forceinline__ int cvt_pk_bf16(float lo, float hi) {
  int d;
  asm("v_cvt_pk_bf16_f32 %0, %1, %2" : "=v"(d) : "v"(lo), "v"(hi));
  return d;
}
static __device__ __forceinline__ void perm32swap_f(float& a, float& b) {
  asm("v_permlane32_swap_b32 %0, %1" : "+v"(a), "+v"(b));
}
static __device__ __forceinline__ float max3f(float a, float b, float c) {
  float d;
  asm("v_max3_f32 %0, %1, %2, %3" : "=v"(d) : "v"(a), "v"(b), "v"(c));
  return d;
}
static __device__ __forceinline__ f32x16 zero16() {
  f32x16 z;
#pragma unroll
  for (int i = 0; i < 16; ++i) z[i] = 0.0f;
  return z;
}
// VGPR-form S-MFMA variants (softmax operand stays out of AGPRs).
// first: s_nop guards VALU C-init -> MFMA read.
// mid:   plain (followed by more MFMAs before any VALU read of dest).
// last:  trailing s_nops guard MFMA write -> VALU read.
static __device__ __forceinline__ void mfma_bf16_first(bf16x8 a, bf16x8 b, f32x16& c) {
  asm("s_nop 1\n\tv_mfma_f32_32x32x16_bf16 %0, %1, %2, %0"
      : "+v"(c) : "v"(a), "v"(b));
}
static __device__ __forceinline__ void mfma_bf16_mid(bf16x8 a, bf16x8 b, f32x16& c) {
  asm("v_mfma_f32_32x32x16_bf16 %0, %1, %2, %0"
      : "+v"(c) : "v"(a), "v"(b));
}
static __device__ __forceinline__ void mfma_bf16_last(bf16x8 a, bf16x8 b, f32x16& c) {
  asm("v_mfma_f32_32x32x16_bf16 %0, %1, %2, %0\n\ts_nop 7\n\ts_nop 7"
      : "+v"(c) : "v"(a), "v"(b));
}
static __device__ __forceinline__ bf16x8 pack8(float f0, float f1, float f2,
    float f3, float f4, float f5, float f6, float f7) {
  union { int w[4]; bf16x8 v8; } u;
  u.w[0] = cvt_pk_bf16(f0, f1);
  u.w[1] = cvt_pk_bf16(f2, f3);
  u.w[2] = cvt_pk_bf16(f4, f5);
  u.w[3] = cvt_pk_bf16(f6, f7);
  return u.v8;
}
static __device__ __forceinline__ ushort f2bfu(float f) {
  union { __hip_bfloat16 h; ushort u; } cv;
  cv.h = __float2bfloat16(f);
  return cv.u;
}
static __device__ __forceinline__ int pack4_fp8(float a, float b, float c, float d) {
  int r = __builtin_amdgcn_cvt_pk_fp8_f32(a, b, 0, false);
  r = __builtin_amdgcn_cvt_pk_fp8_f32(c, d, r, true);
  return r;
}
static __device__ __forceinline__ unsigned char f2fp8(float f) {
  return (unsigned char)(__builtin_amdgcn_cvt_pk_fp8_f32(f, f, 0, false) & 0xff);
}

// Layouts:
//  qT/kT (bf16): [b][mt=n/32][frag=i/16][p]; p = 256*((i>>3)&1) + 8*(n&31) + (i&7)
//  vT8  (fp8):   [b][ct=c/32][nt=n/16][p];  p = 256*((n>>3)&1) + 8*(c&31) + (n&7)

// ---- fused qkv projection, MFMA 32x32x16, 1 wave/block ---------------------
// (round-7 z=5 structure — known good/fast; v-store index is ct-major)
__global__ __launch_bounds__(64, 3) void proj_mfma(
    const float* __restrict__ Wq, const float* __restrict__ bq,
    const float* __restrict__ Wk, const float* __restrict__ bk,
    const float* __restrict__ Wv, const float* __restrict__ bv,
    const float* __restrict__ x,
    ushort* __restrict__ qT, ushort* __restrict__ kT,
    unsigned char* __restrict__ vT8) {
  const int lane = threadIdx.x;
  const int l31 = lane & 31;
  const int h = lane >> 5;
  const int b = blockIdx.x;
  const int n0 = blockIdx.y * 32;
  const int og = blockIdx.z;

  const float* xb = x + (size_t)b * CC * NN + n0 + l31;
  const float* wr0 = (og == 0) ? (Wq + (size_t)l31 * CC)
                               : (Wv + (size_t)((og - 1) * 64 + l31) * CC);
  const float* wr1 = (og == 0) ? (Wk + (size_t)l31 * CC)
                               : (Wv + (size_t)((og - 1) * 64 + 32 + l31) * CC);

  f32x16 acc0 = zero16(), acc1 = zero16();
#pragma unroll 4
  for (int ks = 0; ks < 16; ++ks) {
    const int c = ks * 16 + h * 8;
    const float* xp = xb + (size_t)c * NN;
    bf16x8 xf = pack8(xp[0], xp[(size_t)1 * NN], xp[(size_t)2 * NN],
                      xp[(size_t)3 * NN], xp[(size_t)4 * NN], xp[(size_t)5 * NN],
                      xp[(size_t)6 * NN], xp[(size_t)7 * NN]);
    float4 wa = *(const float4*)(wr0 + c);
    float4 wb = *(const float4*)(wr0 + c + 4);
    bf16x8 wf0 = pack8(wa.x, wa.y, wa.z, wa.w, wb.x, wb.y, wb.z, wb.w);
    float4 wc = *(const float4*)(wr1 + c);
    float4 wd = *(const float4*)(wr1 + c + 4);
    bf16x8 wf1 = pack8(wc.x, wc.y, wc.z, wc.w, wd.x, wd.y, wd.z, wd.w);
    acc0 = __builtin_amdgcn_mfma_f32_32x32x16_bf16(wf0, xf, acc0, 0, 0, 0);
    acc1 = __builtin_amdgcn_mfma_f32_32x32x16_bf16(wf1, xf, acc1, 0, 0, 0);
  }

  if (og == 0) {
    ushort* qb = qT + (size_t)(b * 128 + (n0 >> 5)) * 1024;
    ushort* kb = kT + (size_t)(b * 128 + (n0 >> 5)) * 1024;
#pragma unroll
    for (int r = 0; r < 16; ++r) {
      const int i = (r & 3) + 8 * (r >> 2) + 4 * h;
      const size_t off = (size_t)(i >> 4) * 512 + ((i >> 3) & 1) * 256 + 8 * l31 + (i & 7);
      qb[off] = f2bfu((acc0[r] + bq[i]) * SCALE_Q);
      kb[off] = f2bfu(acc1[r] + bk[i]);
    }
  } else {
    const int n = n0 + l31;
    const size_t nsub = (size_t)(n >> 4) * 512 + ((size_t)((n >> 3) & 1)) * 256 + (n & 7);
    const size_t bbase = (size_t)b * (1 << 20);
#pragma unroll
    for (int r = 0; r < 16; ++r) {
      const int rp = (r & 3) + 8 * (r >> 2) + 4 * h;
      const int c0 = (og - 1) * 64 + rp;
      const int c1 = c0 + 32;
      vT8[bbase + (size_t)(c0 >> 5) * 131072 + nsub + (c0 & 31) * 8] = f2fp8(acc0[r] + bv[c0]);
      vT8[bbase + (size_t)(c1 >> 5) * 131072 + nsub + (c1 & 31) * 8] = f2fp8(acc1[r] + bv[c1]);
    }
  }
}

// ---- flash attention: 8-wave coop, PAIR-unrolled tiles ---------------------
// 1-D grid 512, block 512. Pair p handles 512 keys (tiles 2p,2p+1) with ONE
// B1+B2: {K loads; PV(prev pair)=32 fp8 MFMA; S pair=4 bf16 MFMA; combined
// softmax}. pbuf is 4-slot (slot = tile&3). Barriers: 16 total (was 32).
__global__ __launch_bounds__(512, 4) void flash_coop(
    const ushort* __restrict__ qT, const ushort* __restrict__ kT,
    const unsigned char* __restrict__ vT8, const float* __restrict__ x,
    const float* __restrict__ gamma, float* __restrict__ out) {
  __shared__ __align__(16) unsigned char pbuf[4][32 * 264];  // P fp8, slot=tile&3
  __shared__ float mlds[2][264];  // per-wave rowmax per tile-in-pair
  __shared__ float slds[2][264];  // per-wave rowsum per tile-in-pair

  const int tid = threadIdx.x;
  const int lane = tid & 63;
  const int w = tid >> 6;
  const int q = lane & 31;
  const int h = lane >> 5;

  const int wg = blockIdx.x;
  const int xcd = wg & 7;
  const int b = xcd >> 1;
  const int nt = ((xcd & 1) << 6) + (wg >> 3);
  const int n0 = nt * 32;

  const ushort* qb = qT + (size_t)(b * 128 + nt) * 1024 + lane * 8;
  const bf16x8 qf0 = *reinterpret_cast<const bf16x8*>(qb);
  const bf16x8 qf1 = *reinterpret_cast<const bf16x8*>(qb + 512);

  const ushort* ktb = kT + (size_t)b * 128 * 1024;
  const unsigned char* vtb = vT8 + (size_t)b * (1 << 20) + (size_t)w * 131072 + lane * 8;

  f32x16 accA = zero16(), accB = zero16();
  float m_run = -1e30f, l_run = 0.0f;

  // softmax-pair macro body as a lambda: st0/st1 -> mlds/slds/pbuf slots
  auto softmax_pair = [&](f32x16& st0, f32x16& st1, int slot0, int slot1,
                          bool first_pair) {
    // wave maxes for both tiles
    {
      float m0 = max3f(st0[0], st0[1], st0[2]);
      float m1 = max3f(st0[3], st0[4], st0[5]);
      float m2 = max3f(st0[6], st0[7], st0[8]);
      float m3 = max3f(st0[9], st0[10], st0[11]);
      m0 = max3f(st0[12], st0[13], m0);
      m1 = max3f(st0[14], st0[15], m1);
      float mx = max3f(m0, m1, fmaxf(m2, m3));
      float sw1 = mx, sw2 = mx;
      perm32swap_f(sw1, sw2);
      if (lane < 32) mlds[0][w * 33 + q] = fmaxf(sw1, sw2);
    }
    {
      float m0 = max3f(st1[0], st1[1], st1[2]);
      float m1 = max3f(st1[3], st1[4], st1[5]);
      float m2 = max3f(st1[6], st1[7], st1[8]);
      float m3 = max3f(st1[9], st1[10], st1[11]);
      m0 = max3f(st1[12], st1[13], m0);
      m1 = max3f(st1[14], st1[15], m1);
      float mx = max3f(m0, m1, fmaxf(m2, m3));
      float sw1 = mx, sw2 = mx;
      perm32swap_f(sw1, sw2);
      if (lane < 32) mlds[1][w * 33 + q] = fmaxf(sw1, sw2);
    }
    __syncthreads();  // B1
    float tmax = fmaxf(mlds[0][q], mlds[1][q]);
#pragma unroll
    for (int i = 1; i < 8; ++i)
      tmax = max3f(mlds[0][i * 33 + q], mlds[1][i * 33 + q], tmax);

    if (first_pair) {
      m_run = tmax;
    } else if (__any(tmax > m_run + 8.0f)) {
      const float mnew = fmaxf(m_run, tmax);
      const float f = __builtin_amdgcn_exp2f(m_run - mnew);
#pragma unroll
      for (int r = 0; r < 16; ++r) { accA[r] *= f; accB[r] *= f; }
      l_run *= f;
      m_run = mnew;
    }

#pragma unroll
    for (int r = 0; r < 16; ++r) st0[r] = __builtin_amdgcn_exp2f(st0[r] - m_run);
#pragma unroll
    for (int r = 0; r < 16; ++r) st1[r] = __builtin_amdgcn_exp2f(st1[r] - m_run);
    {
      float s0 = ((st0[0] + st0[1]) + (st0[2] + st0[3])) +
                 ((st0[4] + st0[5]) + (st0[6] + st0[7]));
      float s1 = ((st0[8] + st0[9]) + (st0[10] + st0[11])) +
                 ((st0[12] + st0[13]) + (st0[14] + st0[15]));
      float ps = s0 + s1, pa = ps, pb2 = ps;
      perm32swap_f(pa, pb2);
      if (lane < 32) slds[0][w * 33 + q] = pa + pb2;
    }
    {
      float s0 = ((st1[0] + st1[1]) + (st1[2] + st1[3])) +
                 ((st1[4] + st1[5]) + (st1[6] + st1[7]));
      float s1 = ((st1[8] + st1[9]) + (st1[10] + st1[11])) +
                 ((st1[12] + st1[13]) + (st1[14] + st1[15]));
      float ps = s0 + s1, pa = ps, pb2 = ps;
      perm32swap_f(pa, pb2);
      if (lane < 32) slds[1][w * 33 + q] = pa + pb2;
    }
#pragma unroll
    for (int rg = 0; rg < 4; ++rg) {
      const int pk = pack4_fp8(st0[rg * 4], st0[rg * 4 + 1], st0[rg * 4 + 2], st0[rg * 4 + 3]);
      *reinterpret_cast<int*>(&pbuf[slot0][q * 264 + w * 32 + rg * 8 + h * 4]) = pk;
    }
#pragma unroll
    for (int rg = 0; rg < 4; ++rg) {
      const int pk = pack4_fp8(st1[rg * 4], st1[rg * 4 + 1], st1[rg * 4 + 2], st1[rg * 4 + 3]);
      *reinterpret_cast<int*>(&pbuf[slot1][q * 264 + w * 32 + rg * 8 + h * 4]) = pk;
    }
    __syncthreads();  // B2
    float tsum = slds[0][q] + slds[1][q];
#pragma unroll
    for (int i = 1; i < 8; ++i)
      tsum += slds[0][i * 33 + q] + slds[1][i * 33 + q];
    l_run = (first_pair ? 0.0f : l_run) + tsum;
  };

  auto pv_tile = [&](int tile, int slot) {
    const unsigned char* vc = vtb + (size_t)(tile * 16) * 512;
    const unsigned char* pb = &pbuf[slot][q * 264 + h * 8];
#pragma unroll
    for (int kt = 0; kt < 16; kt += 2) {
      const long vA = *reinterpret_cast<const long*>(vc + kt * 512);
      const long pA = *reinterpret_cast<const long*>(pb + kt * 16);
      accA = __builtin_amdgcn_mfma_f32_32x32x16_fp8_fp8(vA, pA, accA, 0, 0, 0);
      const long vB = *reinterpret_cast<const long*>(vc + (kt + 1) * 512);
      const long pB = *reinterpret_cast<const long*>(pb + (kt + 1) * 16);
      accB = __builtin_amdgcn_mfma_f32_32x32x16_fp8_fp8(vB, pB, accB, 0, 0, 0);
    }
  };

  // ---------------- prologue: pair 0 (tiles 0,1) ---------------------------
  {
    const ushort* kc0 = ktb + (size_t)(0 * 8 + w) * 1024 + lane * 8;
    const ushort* kc1 = ktb + (size_t)(1 * 8 + w) * 1024 + lane * 8;
    const bf16x8 ka0 = *reinterpret_cast<const bf16x8*>(kc0);
    const bf16x8 ka1 = *reinterpret_cast<const bf16x8*>(kc0 + 512);
    const bf16x8 kb0 = *reinterpret_cast<const bf16x8*>(kc1);
    const bf16x8 kb1 = *reinterpret_cast<const bf16x8*>(kc1 + 512);
    f32x16 st0 = zero16(), st1 = zero16();
    mfma_bf16_first(ka0, qf0, st0);
    mfma_bf16_mid(ka1, qf1, st0);
    mfma_bf16_first(kb0, qf0, st1);
    mfma_bf16_last(kb1, qf1, st1);
    softmax_pair(st0, st1, 0, 1, true);
  }

  // ---------------- main loop: pairs p = 1..7 ------------------------------
  for (int p = 1; p < 8; ++p) {
    const int t0 = 2 * p, t1 = 2 * p + 1;
    const int r0 = t0 - 2, r1 = t1 - 2;

    // K loads for this pair (latency hidden under PV cluster)
    const ushort* kc0 = ktb + (size_t)(t0 * 8 + w) * 1024 + lane * 8;
    const ushort* kc1 = ktb + (size_t)(t1 * 8 + w) * 1024 + lane * 8;
    const bf16x8 ka0 = *reinterpret_cast<const bf16x8*>(kc0);
    const bf16x8 ka1 = *reinterpret_cast<const bf16x8*>(kc0 + 512);
    const bf16x8 kb0 = *reinterpret_cast<const bf16x8*>(kc1);
    const bf16x8 kb1 = *reinterpret_cast<const bf16x8*>(kc1 + 512);

    // PV of previous pair: 32 fp8 MFMA cluster
    __builtin_amdgcn_s_setprio(1);
    pv_tile(r0, r0 & 3);
    pv_tile(r1, r1 & 3);

    // S pair: 4 bf16 MFMA
    f32x16 st0 = zero16(), st1 = zero16();
    mfma_bf16_first(ka0, qf0, st0);
    mfma_bf16_mid(ka1, qf1, st0);
    mfma_bf16_first(kb0, qf0, st1);
    mfma_bf16_last(kb1, qf1, st1);
    __builtin_amdgcn_s_setprio(0);

    softmax_pair(st0, st1, t0 & 3, t1 & 3, false);
  }

  // ---------------- epilogue: PV(14), PV(15) -------------------------------
  __builtin_amdgcn_s_setprio(1);
  pv_tile(14, 2);
  pv_tile(15, 3);
  __builtin_amdgcn_s_setprio(0);

  // ---- epilogue: out = gamma * O/l + x ----
  const float g = gamma[0];
  const float linv = 1.0f / l_run;
#pragma unroll
  for (int r = 0; r < 16; ++r) {
    const int c = w * 32 + (r & 3) + 8 * (r >> 2) + 4 * h;
    const size_t idx = ((size_t)b * CC + c) * NN + n0 + q;
    out[idx] = g * (accA[r] + accB[r]) * linv + x[idx];
  }
}

extern "C" void kernel_launch(void* const* d_in, const int* in_sizes, int n_in,
                              void* d_out, int out_size, void* d_ws, size_t ws_size,
                              hipStream_t stream) {
  const float* x = (const float*)d_in[0];
  const float* Wq = (const float*)d_in[1];
  const float* bq = (const float*)d_in[2];
  const float* Wk = (const float*)d_in[3];
  const float* bk = (const float*)d_in[4];
  const float* Wv = (const float*)d_in[5];
  const float* bv = (const float*)d_in[6];
  const float* gamma = (const float*)d_in[7];
  float* out = (float*)d_out;

  ushort* qT = (ushort*)d_ws;                          // B*128*1024 bf16
  ushort* kT = qT + (size_t)BB * 128 * 1024;           // B*128*1024 bf16
  unsigned char* vT8 = (unsigned char*)(kT + (size_t)BB * 128 * 1024);  // B*1MB fp8

  proj_mfma<<<dim3(BB, NN / 32, 5), dim3(64), 0, stream>>>(
      Wq, bq, Wk, bk, Wv, bv, x, qT, kT, vT8);
  flash_coop<<<dim3(512), dim3(512), 0, stream>>>(
      qT, kT, vT8, x, gamma, out);
}